// Round 7
// baseline (3770.716 us; speedup 1.0000x reference)
//
#include <hip/hip_runtime.h>
#include <hip/hip_bf16.h>
#include <cstdint>

#define NH 12
#define SQ 197
#define DIM 768
#define HDIM 64
#define BATCH 64
#define MTOK (BATCH*SQ)   // 12608
#define MLPD 3072
#define NKEEP 98
#define CSLOT 100         // compact slots per image (98/99 kept + pad)
#define MCTOK (BATCH*CSLOT) // 6400
#define VLDF 224          // padded V cols, full mode (7*32)
#define VLDC 128          // padded V cols, compact mode (4*32)

typedef __attribute__((ext_vector_type(8))) short bf16x8;
typedef __attribute__((ext_vector_type(8))) unsigned short ushort8;
typedef __attribute__((ext_vector_type(4))) float floatx4;

// Native RTNE f32->bf16 (compiler emits v_cvt_pk_bf16_f32 for pairs, m240).
__device__ __forceinline__ unsigned short f2bf(float f) {
  __hip_bfloat16 h = __float2bfloat16(f);
  return reinterpret_cast<unsigned short&>(h);
}

// A&S 7.1.26 erf: |err| <= 1.5e-7 (<< bf16 ulp), ~12 VALU ops vs ~30+ libm.
__device__ __forceinline__ float erf_fast(float x) {
  float ax = fabsf(x);
  float t = 1.f / (1.f + 0.3275911f * ax);
  float y = t * (0.254829592f + t * (-0.284496736f + t * (1.421413741f +
            t * (-1.453152027f + t * 1.061405429f))));
  float r = 1.f - y * __expf(-ax * ax);
  return copysignf(r, x);
}

// async global->LDS, 16B per lane. LDS dest is wave-uniform base + lane*16.
__device__ __forceinline__ void gload16(const unsigned short* g, unsigned short* l) {
  __builtin_amdgcn_global_load_lds(
      (const __attribute__((address_space(1))) void*)g,
      (__attribute__((address_space(3))) void*)l, 16, 0, 0);
}

enum { EPI_PATCH = 0, EPI_QKV = 1, EPI_RESID = 2, EPI_GELU = 3, EPI_HEAD = 4, EPI_QKVC = 5 };

// Shared epilogue. C/D layout col=lane&15, row=(lane>>4)*4+j [verified m89/m91]
// CHK=false: block fully interior (no per-element bounds tests).
template<int EPI, bool CHK, int MR, int NR>
__device__ __forceinline__ void gemm_epilogue(
    floatx4 (&acc)[MR][NR], int m0, int n0, int wr, int wc, int l15, int l4,
    const float* __restrict__ bias, int M, int N,
    float* __restrict__ xresid, const float* __restrict__ pos,
    unsigned short* __restrict__ obf, unsigned short* __restrict__ qb,
    unsigned short* __restrict__ kb, unsigned short* __restrict__ vb,
    float* __restrict__ ofp)
{
#pragma unroll
  for (int mr = 0; mr < MR; ++mr) {
#pragma unroll
    for (int nr = 0; nr < NR; ++nr) {
#pragma unroll
      for (int j = 0; j < 4; ++j) {
        int m = m0 + wr + mr * 16 + l4 * 4 + j;
        int n = n0 + wc + nr * 16 + l15;
        if (CHK && (m >= M || n >= N)) continue;
        float val = acc[mr][nr][j] + bias[n];
        if constexpr (EPI == EPI_PATCH) {
          int b = m / 196, p = m - b * 196;
          xresid[(size_t)(b * SQ + 1 + p) * DIM + n] = val + pos[(1 + p) * DIM + n];
        } else if constexpr (EPI == EPI_QKV || EPI == EPI_QKVC) {
          constexpr int SR = (EPI == EPI_QKV) ? SQ : CSLOT;
          constexpr int VL = (EPI == EPI_QKV) ? VLDF : VLDC;
          int part = n / DIM; int within = n - part * DIM;
          int h = within >> 6, hd = within & 63;
          int b = m / SR, s = m - b * SR;
          if (part == 0)      qb[(((size_t)(b * NH + h)) * SR + s) * HDIM + hd] = f2bf(val * 0.125f);
          else if (part == 1) kb[(((size_t)(b * NH + h)) * SR + s) * HDIM + hd] = f2bf(val);
          else                vb[(((size_t)(b * NH + h)) * HDIM + hd) * VL + s] = f2bf(val);
        } else if constexpr (EPI == EPI_RESID) {
          xresid[(size_t)m * DIM + n] += val;
        } else if constexpr (EPI == EPI_GELU) {
          float g = 0.5f * val * (1.f + erf_fast(val * 0.70710678118654752f));
          obf[(size_t)m * MLPD + n] = f2bf(g);
        } else {
          ofp[(size_t)m * 1000 + n] = val;
        }
      }
    }
  }
}

// ------------------------------- GEMM 256x256, 8 waves, 2-phase (main) ----
// C[M,N] = A[M,K](bf16) @ W[N,K](bf16)^T + bias. BM=BN=256, BK=64,
// 8 waves as 2M x 4N (wave tile 128x64, acc[8][4]), 128 KiB dbuf LDS.
// 2-phase counted-vmcnt loop (r5-proven sync): STAGE(next) -> vmcnt(8)
// -> barrier -> MFMA(cur) -> barrier. Per-wave 64 MFMA/K-step vs 8 loads
// amortizes the stage+barrier stall that capped the 128-tile structure
// (m230: 2ph gates at 256-sq, 682 TF). Staging: global_load_lds_dwordx4,
// linear LDS dest + pre-swizzled global source (rule #21) -> conflict-free
// swizzled ds_read_b128. T1 bijective XCD swizzle (m204).
template<int EPI>
__global__ __launch_bounds__(512, 2)
void gemm_bf256(const unsigned short* __restrict__ A, int lda,
                const unsigned short* __restrict__ Wb, int ldw,
                const float* __restrict__ bias,
                int M, int N, int K,
                float* __restrict__ xresid,
                const float* __restrict__ pos,
                unsigned short* __restrict__ obf,
                unsigned short* __restrict__ qb,
                unsigned short* __restrict__ kb,
                unsigned short* __restrict__ vb,
                float* __restrict__ ofp)
{
  __shared__ unsigned short As[2][256 * 64];   // 64 KiB
  __shared__ unsigned short Bs[2][256 * 64];   // 64 KiB
  const int tid = threadIdx.x;
  const int lane = tid & 63;
  const int w = tid >> 6;               // 0..7
  const int wr = (w >> 2) * 128;        // 2 M-waves
  const int wc = (w & 3) * 64;          // 4 N-waves

  // T1 bijective XCD swizzle (m204)
  const int gx = gridDim.x;
  const int nwg = gx * gridDim.y;
  const int orig = blockIdx.y * gx + blockIdx.x;
  const int q = nwg >> 3, r = nwg & 7;
  const int xcd = orig & 7, o8 = orig >> 3;
  const int wgid = ((xcd < r) ? xcd * (q + 1) : r * (q + 1) + (xcd - r) * q) + o8;
  const int bx = wgid % gx, by = wgid / gx;
  const int m0 = by * 256, n0 = bx * 256;
  const int l15 = lane & 15, l4 = lane >> 4;

  // staging: waves 0-3 load A (rows 0..255), waves 4-7 load B.
  // per wave 8 groups of 8 rows; lane covers row rsub of group, chunk sub.
  // pre-swizzled source chunk = sub ^ rsub (row&7 == rsub for 8-row groups).
  const int sub = lane & 7, rsub = lane >> 3;
  const int scol = ((sub ^ rsub) << 3);
  const bool isA = (w < 4);
  const unsigned short* gp[8];
  int ldst[8];
#pragma unroll
  for (int j = 0; j < 8; ++j) {
    int row = (w & 3) * 64 + j * 8 + rsub;          // row within 256-tile
    if (isA) {
      int ra = m0 + row; if (ra > M - 1) ra = M - 1;
      gp[j] = A + (size_t)ra * lda + scol;
    } else {
      int rb = n0 + row; if (rb > N - 1) rb = N - 1;
      gp[j] = Wb + (size_t)rb * ldw + scol;
    }
    ldst[j] = ((w & 3) * 8 + j) * 512;              // short offset in buffer
  }

  floatx4 acc[8][4];
#pragma unroll
  for (int i = 0; i < 8; ++i)
#pragma unroll
    for (int j = 0; j < 4; ++j) acc[i][j] = {0.f, 0.f, 0.f, 0.f};

  auto STAGE = [&](int buf, int kt) {
    unsigned short* base = isA ? &As[buf][0] : &Bs[buf][0];
#pragma unroll
    for (int j = 0; j < 8; ++j)
      gload16(gp[j] + kt, base + ldst[j]);
  };

  const int nk = K >> 6;
  STAGE(0, 0);                 // 8 loads/lane in flight
  int cur = 0;
  for (int ki = 0; ki < nk; ++ki) {
    if (ki + 1 < nk) {
      STAGE(cur ^ 1, (ki + 1) << 6);                    // 16 in flight
      asm volatile("s_waitcnt vmcnt(8)" ::: "memory");  // cur's 8 landed
    } else {
      asm volatile("s_waitcnt vmcnt(0)" ::: "memory");
    }
    __builtin_amdgcn_sched_barrier(0);
    __builtin_amdgcn_s_barrier();            // tile[cur] visible to all waves
    const unsigned short* Ac = &As[cur][0];
    const unsigned short* Bc = &Bs[cur][0];
#pragma unroll
    for (int kk = 0; kk < 2; ++kk) {
      bf16x8 af[8], bfr[4];
#pragma unroll
      for (int mr = 0; mr < 8; ++mr) {
        int row = wr + mr * 16 + l15;
        int cs = (kk * 4 + l4) ^ (row & 7);
        af[mr] = *(const bf16x8*)&Ac[row * 64 + cs * 8];
      }
#pragma unroll
      for (int nr = 0; nr < 4; ++nr) {
        int row = wc + nr * 16 + l15;
        int cs = (kk * 4 + l4) ^ (row & 7);
        bfr[nr] = *(const bf16x8*)&Bc[row * 64 + cs * 8];
      }
#pragma unroll
      for (int mr = 0; mr < 8; ++mr)
#pragma unroll
        for (int nr = 0; nr < 4; ++nr)
          acc[mr][nr] = __builtin_amdgcn_mfma_f32_16x16x32_bf16(af[mr], bfr[nr], acc[mr][nr], 0, 0, 0);
    }
    __builtin_amdgcn_sched_barrier(0);
    __builtin_amdgcn_s_barrier();            // all waves done reading tile[cur]
    cur ^= 1;
  }
  if (m0 + 256 <= M && n0 + 256 <= N)
    gemm_epilogue<EPI, false, 8, 4>(acc, m0, n0, wr, wc, l15, l4, bias, M, N,
                                    xresid, pos, obf, qb, kb, vb, ofp);
  else
    gemm_epilogue<EPI, true, 8, 4>(acc, m0, n0, wr, wc, l15, l4, bias, M, N,
                                   xresid, pos, obf, qb, kb, vb, ofp);
}

// --------------------------------- GEMM 128xBN, 4 waves, 1-phase (small) --
// For N=768-class GEMMs (proj/fc2/patch/head) where grids need many blocks.
template<int EPI, int BN>
__global__ __launch_bounds__(256)
void gemm_bf(const unsigned short* __restrict__ A, int lda,
             const unsigned short* __restrict__ Wb, int ldw,
             const float* __restrict__ bias,
             int M, int N, int K,
             float* __restrict__ xresid,
             const float* __restrict__ pos,
             unsigned short* __restrict__ obf,
             unsigned short* __restrict__ qb,
             unsigned short* __restrict__ kb,
             unsigned short* __restrict__ vb,
             float* __restrict__ ofp)
{
  constexpr int NR = BN / 32;
  constexpr int NG = (128 + BN) / 8;
  constexpr int PG = NG / 4;
  __shared__ unsigned short As[128 * 64];
  __shared__ unsigned short Bs[BN * 64];
  const int tid = threadIdx.x;
  const int lane = tid & 63;
  const int w = tid >> 6;
  const int wr = (w >> 1) * 64, wc = (w & 1) * (BN / 2);

  const int gx = gridDim.x;
  const int nwg = gx * gridDim.y;
  const int orig = blockIdx.y * gx + blockIdx.x;
  const int q = nwg >> 3, r = nwg & 7;
  const int xcd = orig & 7, o8 = orig >> 3;
  const int wgid = ((xcd < r) ? xcd * (q + 1) : r * (q + 1) + (xcd - r) * q) + o8;
  const int bx = wgid % gx, by = wgid / gx;
  const int m0 = by * 128, n0 = bx * BN;
  const int l15 = lane & 15, l4 = lane >> 4;

  const int sub = lane & 7, rsub = lane >> 3;
  const int scol = ((sub ^ rsub) << 3);
  const unsigned short* gp[PG];
  unsigned short* lp[PG];
#pragma unroll
  for (int j = 0; j < PG; ++j) {
    int t = w * PG + j;
    if (t < 16) {
      int row = t * 8 + rsub;
      int ra = m0 + row; if (ra > M - 1) ra = M - 1;
      gp[j] = A + (size_t)ra * lda + scol;
      lp[j] = &As[t * 512];
    } else {
      int tb = t - 16;
      int row = tb * 8 + rsub;
      int rb = n0 + row; if (rb > N - 1) rb = N - 1;
      gp[j] = Wb + (size_t)rb * ldw + scol;
      lp[j] = &Bs[tb * 512];
    }
  }

  floatx4 acc[4][NR];
#pragma unroll
  for (int i = 0; i < 4; ++i)
#pragma unroll
    for (int j = 0; j < NR; ++j) acc[i][j] = {0.f, 0.f, 0.f, 0.f};

  for (int kt = 0; kt < K; kt += 64) {
#pragma unroll
    for (int j = 0; j < PG; ++j)
      gload16(gp[j] + kt, lp[j]);
    __syncthreads();
#pragma unroll
    for (int kk = 0; kk < 2; ++kk) {
      bf16x8 af[4], bfr[NR];
#pragma unroll
      for (int mr = 0; mr < 4; ++mr) {
        int row = wr + mr * 16 + l15;
        int cs = (kk * 4 + l4) ^ (row & 7);
        af[mr] = *(const bf16x8*)&As[row * 64 + cs * 8];
      }
#pragma unroll
      for (int nr = 0; nr < NR; ++nr) {
        int row = wc + nr * 16 + l15;
        int cs = (kk * 4 + l4) ^ (row & 7);
        bfr[nr] = *(const bf16x8*)&Bs[row * 64 + cs * 8];
      }
#pragma unroll
      for (int mr = 0; mr < 4; ++mr)
#pragma unroll
        for (int nr = 0; nr < NR; ++nr)
          acc[mr][nr] = __builtin_amdgcn_mfma_f32_16x16x32_bf16(af[mr], bfr[nr], acc[mr][nr], 0, 0, 0);
    }
    __syncthreads();
  }
  if (m0 + 128 <= M && n0 + BN <= N)
    gemm_epilogue<EPI, false, 4, NR>(acc, m0, n0, wr, wc, l15, l4, bias, M, N,
                                     xresid, pos, obf, qb, kb, vb, ofp);
  else
    gemm_epilogue<EPI, true, 4, NR>(acc, m0, n0, wr, wc, l15, l4, bias, M, N,
                                    xresid, pos, obf, qb, kb, vb, ofp);
}

// ------------------------------------- GEMM, f32 W (fallback, reg-staged) --
template<int EPI>
__global__ __launch_bounds__(256)
void gemm_f32(const unsigned short* __restrict__ A, int lda,
              const float* __restrict__ Wf, int ldw,
              const float* __restrict__ bias,
              int M, int N, int K,
              float* __restrict__ xresid,
              const float* __restrict__ pos,
              unsigned short* __restrict__ obf,
              unsigned short* __restrict__ qb,
              unsigned short* __restrict__ kb,
              unsigned short* __restrict__ vb,
              float* __restrict__ ofp)
{
  __shared__ unsigned short As[128 * 64];
  __shared__ unsigned short Bs[128 * 64];
  const int tid = threadIdx.x;
  const int lane = tid & 63;
  const int w = tid >> 6;
  const int wr = (w >> 1) * 64, wc = (w & 1) * 64;
  const int m0 = blockIdx.y * 128, n0 = blockIdx.x * 128;
  const int l15 = lane & 15, l4 = lane >> 4;

  floatx4 acc[4][4];
#pragma unroll
  for (int i = 0; i < 4; ++i)
#pragma unroll
    for (int j = 0; j < 4; ++j) acc[i][j] = {0.f, 0.f, 0.f, 0.f};

  for (int kt = 0; kt < K; kt += 64) {
#pragma unroll
    for (int i = 0; i < 4; ++i) {
      int g = tid + 256 * i;
      int row = g >> 3, c = g & 7;
      int sw = (c ^ (row & 7)) * 8;
      int ra = m0 + row; if (ra > M - 1) ra = M - 1;
      ushort8 av = *(const ushort8*)(A + (size_t)ra * lda + kt + c * 8);
      *(ushort8*)&As[row * 64 + sw] = av;
      int rb = n0 + row; if (rb > N - 1) rb = N - 1;
      const float* bs = Wf + (size_t)rb * ldw + kt + c * 8;
      float4 f0 = *(const float4*)bs;
      float4 f1 = *(const float4*)(bs + 4);
      ushort8 bv;
      bv[0] = f2bf(f0.x); bv[1] = f2bf(f0.y); bv[2] = f2bf(f0.z); bv[3] = f2bf(f0.w);
      bv[4] = f2bf(f1.x); bv[5] = f2bf(f1.y); bv[6] = f2bf(f1.z); bv[7] = f2bf(f1.w);
      *(ushort8*)&Bs[row * 64 + sw] = bv;
    }
    __syncthreads();
#pragma unroll
    for (int kk = 0; kk < 2; ++kk) {
      bf16x8 af[4], bfr[4];
#pragma unroll
      for (int mr = 0; mr < 4; ++mr) {
        int row = wr + mr * 16 + l15;
        int cs = (kk * 4 + l4) ^ (row & 7);
        af[mr] = *(const bf16x8*)&As[row * 64 + cs * 8];
      }
#pragma unroll
      for (int nr = 0; nr < 4; ++nr) {
        int row = wc + nr * 16 + l15;
        int cs = (kk * 4 + l4) ^ (row & 7);
        bfr[nr] = *(const bf16x8*)&Bs[row * 64 + cs * 8];
      }
#pragma unroll
      for (int mr = 0; mr < 4; ++mr)
#pragma unroll
        for (int nr = 0; nr < 4; ++nr)
          acc[mr][nr] = __builtin_amdgcn_mfma_f32_16x16x32_bf16(af[mr], bfr[nr], acc[mr][nr], 0, 0, 0);
    }
    __syncthreads();
  }
  if (m0 + 128 <= M && n0 + 128 <= N)
    gemm_epilogue<EPI, false, 4, 4>(acc, m0, n0, wr, wc, l15, l4, bias, M, N,
                                    xresid, pos, obf, qb, kb, vb, ofp);
  else
    gemm_epilogue<EPI, true, 4, 4>(acc, m0, n0, wr, wc, l15, l4, bias, M, N,
                                   xresid, pos, obf, qb, kb, vb, ofp);
}

// ------------------------------------------------------- weight convert --
__global__ __launch_bounds__(256)
void cvt_kernel(const float* __restrict__ src, unsigned short* __restrict__ dst, int nchunks)
{
  int i = blockIdx.x * 256 + threadIdx.x;
  if (i >= nchunks) return;
  float4 f0 = *(const float4*)(src + (size_t)i * 8);
  float4 f1 = *(const float4*)(src + (size_t)i * 8 + 4);
  ushort8 v;
  v[0] = f2bf(f0.x); v[1] = f2bf(f0.y); v[2] = f2bf(f0.z); v[3] = f2bf(f0.w);
  v[4] = f2bf(f1.x); v[5] = f2bf(f1.y); v[6] = f2bf(f1.z); v[7] = f2bf(f1.w);
  *(ushort8*)(dst + (size_t)i * 8) = v;
}

// ------------------------------------------------------------- LayerNorm --
__global__ __launch_bounds__(256)
void ln_kernel(const float* __restrict__ x, long long row_stride,
               const float* __restrict__ g, const float* __restrict__ b,
               unsigned short* __restrict__ out)
{
  int row = blockIdx.x;
  const float* xr = x + (size_t)row * row_stride;
  int t = threadIdx.x;
  float v0 = xr[t], v1 = xr[t + 256], v2 = xr[t + 512];
  float s = v0 + v1 + v2, sq = v0 * v0 + v1 * v1 + v2 * v2;
  __shared__ float sb[8];
  for (int o = 32; o; o >>= 1) { s += __shfl_down(s, o); sq += __shfl_down(sq, o); }
  if ((t & 63) == 0) { sb[t >> 6] = s; sb[4 + (t >> 6)] = sq; }
  __syncthreads();
  s = sb[0] + sb[1] + sb[2] + sb[3];
  sq = sb[4] + sb[5] + sb[6] + sb[7];
  float mean = s * (1.f / 768.f);
  float var = sq * (1.f / 768.f) - mean * mean;
  float rstd = rsqrtf(var + 1e-6f);
  unsigned short* orow = out + (size_t)row * DIM;
  orow[t]       = f2bf((v0 - mean) * rstd * g[t]       + b[t]);
  orow[t + 256] = f2bf((v1 - mean) * rstd * g[t + 256] + b[t + 256]);
  orow[t + 512] = f2bf((v2 - mean) * rstd * g[t + 512] + b[t + 512]);
}

// ------------------------------------------------------------- Attention --
template<int NT, int SROWS, int VLD, int PSTR, bool CNT>
__global__ __launch_bounds__(256)
void attn_kernel(const unsigned short* __restrict__ qb,
                 const unsigned short* __restrict__ kb,
                 const unsigned short* __restrict__ vb,
                 const int* __restrict__ cnt,
                 unsigned short* __restrict__ outA)
{
  __shared__ unsigned short Ks[NT * 16 * 64];
  __shared__ unsigned short Ps[4][16 * PSTR];
  int bh = blockIdx.x;
  int b = bh / NH, h = bh - b * NH;
  const int tid = threadIdx.x, lane = tid & 63, w = tid >> 6;
  const int l15 = lane & 15, l4 = lane >> 4;
  const unsigned short* kbase = kb + (size_t)bh * SROWS * HDIM;
  const unsigned short* qbase = qb + (size_t)bh * SROWS * HDIM;
  const unsigned short* vbase = vb + (size_t)bh * HDIM * VLD;
  const int limit = CNT ? cnt[b] : SROWS;

  constexpr int KCH = NT * 16 * 8;
  for (int i = 0; i < (KCH + 255) / 256; ++i) {
    int gch = tid + 256 * i;
    if (gch < KCH) {
      int row = gch >> 3, c = gch & 7;
      int rs = row > SROWS - 1 ? SROWS - 1 : row;
      ushort8 kv = *(const ushort8*)(kbase + (size_t)rs * HDIM + c * 8);
      *(ushort8*)&Ks[row * 64 + ((c ^ (row & 7))) * 8] = kv;
    }
  }
  __syncthreads();

  for (int qt = w; qt < NT; qt += 4) {
    int qrow = qt * 16 + l15; if (qrow > SROWS - 1) qrow = SROWS - 1;
    bf16x8 aq0 = *(const bf16x8*)(qbase + (size_t)qrow * HDIM + l4 * 8);
    bf16x8 aq1 = *(const bf16x8*)(qbase + (size_t)qrow * HDIM + 32 + l4 * 8);

    floatx4 lg[NT];
#pragma unroll
    for (int nt = 0; nt < NT; ++nt) {
      lg[nt] = {0.f, 0.f, 0.f, 0.f};
      int row = nt * 16 + l15;
      int cs0 = (l4) ^ (row & 7);
      int cs1 = (4 + l4) ^ (row & 7);
      bf16x8 bk0 = *(const bf16x8*)&Ks[row * 64 + cs0 * 8];
      bf16x8 bk1 = *(const bf16x8*)&Ks[row * 64 + cs1 * 8];
      lg[nt] = __builtin_amdgcn_mfma_f32_16x16x32_bf16(aq0, bk0, lg[nt], 0, 0, 0);
      lg[nt] = __builtin_amdgcn_mfma_f32_16x16x32_bf16(aq1, bk1, lg[nt], 0, 0, 0);
    }
    float mx[4] = {-1e30f, -1e30f, -1e30f, -1e30f};
#pragma unroll
    for (int nt = 0; nt < NT; ++nt) {
      int col = nt * 16 + l15;
      bool valid = col < limit;
#pragma unroll
      for (int j = 0; j < 4; ++j) {
        float v = valid ? lg[nt][j] : -1e9f;
        lg[nt][j] = v;
        mx[j] = fmaxf(mx[j], v);
      }
    }
#pragma unroll
    for (int j = 0; j < 4; ++j)
      for (int o = 1; o < 16; o <<= 1) mx[j] = fmaxf(mx[j], __shfl_xor(mx[j], o));
    float sm[4] = {0.f, 0.f, 0.f, 0.f};
#pragma unroll
    for (int nt = 0; nt < NT; ++nt)
#pragma unroll
      for (int j = 0; j < 4; ++j) {
        float p = __expf(lg[nt][j] - mx[j]);
        lg[nt][j] = p;
        sm[j] += p;
      }
#pragma unroll
    for (int j = 0; j < 4; ++j) {
      for (int o = 1; o < 16; o <<= 1) sm[j] += __shfl_xor(sm[j], o);
      sm[j] = 1.f / sm[j];
    }
    unsigned short* pw = &Ps[w][0];
#pragma unroll
    for (int nt = 0; nt < NT; ++nt) {
      int col = nt * 16 + l15;
#pragma unroll
      for (int j = 0; j < 4; ++j)
        pw[(l4 * 4 + j) * PSTR + col] = f2bf(lg[nt][j]);
    }
#pragma unroll
    for (int j = 0; j < 4; ++j)
      pw[(l4 * 4 + j) * PSTR + NT * 16 + l15] = 0;
    floatx4 oacc[4];
#pragma unroll
    for (int nr = 0; nr < 4; ++nr) oacc[nr] = {0.f, 0.f, 0.f, 0.f};
#pragma unroll
    for (int ks = 0; ks < VLD / 32; ++ks) {
      bf16x8 ap = *(const bf16x8*)&pw[l15 * PSTR + ks * 32 + l4 * 8];
#pragma unroll
      for (int nr = 0; nr < 4; ++nr) {
        bf16x8 bv = *(const bf16x8*)(vbase + (size_t)(nr * 16 + l15) * VLD + ks * 32 + l4 * 8);
        oacc[nr] = __builtin_amdgcn_mfma_f32_16x16x32_bf16(ap, bv, oacc[nr], 0, 0, 0);
      }
    }
#pragma unroll
    for (int nr = 0; nr < 4; ++nr)
#pragma unroll
      for (int j = 0; j < 4; ++j) {
        int qi = qt * 16 + l4 * 4 + j;
        if (qi < SROWS)
          outA[((size_t)(b * SROWS + qi)) * DIM + h * HDIM + nr * 16 + l15] = f2bf(oacc[nr][j] * sm[j]);
      }
  }
}

// ---------------------------------------------------------------- im2col --
__global__ __launch_bounds__(256)
void im2col_kernel(const float* __restrict__ images, unsigned short* __restrict__ out)
{
  int idx = blockIdx.x * 256 + threadIdx.x;
  int token = idx / 96;
  int kc = (idx - token * 96) * 8;
  int b = token / 196, p = token - b * 196;
  int py = p / 14, px = p - py * 14;
  int c = kc >> 8, rem = kc & 255;
  int i = rem >> 4, j0 = rem & 15;
  const float* src = images + (((size_t)(b * 3 + c) * 224 + py * 16 + i) * 224 + px * 16 + j0);
  float4 f0 = *(const float4*)src;
  float4 f1 = *(const float4*)(src + 4);
  ushort8 v;
  v[0] = f2bf(f0.x); v[1] = f2bf(f0.y); v[2] = f2bf(f0.z); v[3] = f2bf(f0.w);
  v[4] = f2bf(f1.x); v[5] = f2bf(f1.y); v[6] = f2bf(f1.z); v[7] = f2bf(f1.w);
  *(ushort8*)(out + (size_t)token * DIM + kc) = v;
}

__global__ __launch_bounds__(256)
void clspos_kernel(const float* __restrict__ cls, const float* __restrict__ pos,
                   float* __restrict__ x)
{
  int idx = blockIdx.x * 256 + threadIdx.x;
  int b = idx / DIM, d = idx - b * DIM;
  x[(size_t)(b * SQ) * DIM + d] = cls[d] + pos[d];
}

// ----------------------------------------------- top-k (3 parallel stages) --
__global__ __launch_bounds__(256)
void norms_kernel(const float* __restrict__ x, float* __restrict__ norms)
{
  int row = blockIdx.x * 4 + (threadIdx.x >> 6);
  if (row >= MTOK) return;
  int lane = threadIdx.x & 63;
  const float* xr = x + (size_t)row * DIM;
  float acc = 0.f;
  for (int d = lane; d < DIM; d += 64) { float v = xr[d]; acc += v * v; }
  for (int o = 32; o; o >>= 1) acc += __shfl_down(acc, o);
  if (lane == 0) norms[row] = acc;
}

// Rank-count selection == jax.lax.top_k (desc, stable ties -> lower index).
__global__ __launch_bounds__(256)
void topk_select(const float* __restrict__ norms, short* __restrict__ sidx,
                 int* __restrict__ cntg)
{
  int b = blockIdx.x;
  __shared__ float sc[SQ];
  __shared__ unsigned char keep[SQ];
  int tid = threadIdx.x;
  if (tid < SQ) sc[tid] = norms[b * SQ + tid];
  __syncthreads();
  if (tid < SQ) {
    float mine = sc[tid];
    int rank = 0;
    for (int j = 0; j < SQ; ++j) {
      float v = sc[j];
      rank += (v > mine) || (v == mine && j < tid);
    }
    keep[tid] = (rank < NKEEP) || (tid == 0);
  }
  __syncthreads();
  if (tid == 0) {
    short* row = sidx + b * CSLOT;
    int c = 0;
    for (int s = 0; s < SQ; ++s) if (keep[s]) row[c++] = (short)s;
    cntg[b] = c;
    for (int s = c; s < CSLOT; ++s) row[s] = 0;  // pad slots copy row 0
  }
}

__global__ __launch_bounds__(192)
void gather_kernel(const float* __restrict__ x, const short* __restrict__ sidx,
                   float* __restrict__ xc)
{
  int g = blockIdx.x;              // b*CSLOT + slot
  int b = g / CSLOT;
  int src = sidx[g];
  const float4* sp = (const float4*)(x + ((size_t)(b * SQ + src)) * DIM);
  float4* dp = (float4*)(xc + (size_t)g * DIM);
  dp[threadIdx.x] = sp[threadIdx.x];
}

// ------------------------------------------------------------------ host --
template<int EPI, int BN>
static inline void launch_gemm(hipStream_t stream, bool usebf,
                               const unsigned short* A, int lda,
                               const float* Wf, const unsigned short* Wb, int ldw,
                               const float* bias, int M, int N, int K,
                               float* xresid, const float* pos,
                               unsigned short* obf, unsigned short* qb,
                               unsigned short* kb, unsigned short* vb, float* ofp)
{
  if (usebf) {
    dim3 grid((N + BN - 1) / BN, (M + 127) / 128);
    gemm_bf<EPI, BN><<<grid, 256, 0, stream>>>(A, lda, Wb, ldw, bias,
        M, N, K, xresid, pos, obf, qb, kb, vb, ofp);
  } else {
    dim3 grid((N + 127) / 128, (M + 127) / 128);
    gemm_f32<EPI><<<grid, 256, 0, stream>>>(A, lda, Wf, ldw, bias,
        M, N, K, xresid, pos, obf, qb, kb, vb, ofp);
  }
}

template<int EPI>
static inline void launch_gemm256(hipStream_t stream, bool usebf,
                                  const unsigned short* A, int lda,
                                  const float* Wf, const unsigned short* Wb, int ldw,
                                  const float* bias, int M, int N, int K,
                                  unsigned short* obf, unsigned short* qb,
                                  unsigned short* kb, unsigned short* vb)
{
  if (usebf) {
    dim3 grid(N / 256, (M + 255) / 256);
    gemm_bf256<EPI><<<grid, 512, 0, stream>>>(A, lda, Wb, ldw, bias,
        M, N, K, nullptr, nullptr, obf, qb, kb, vb, nullptr);
  } else {
    dim3 grid((N + 127) / 128, (M + 127) / 128);
    gemm_f32<EPI><<<grid, 256, 0, stream>>>(A, lda, Wf, ldw, bias,
        M, N, K, nullptr, nullptr, obf, qb, kb, vb, nullptr);
  }
}

extern "C" void kernel_launch(void* const* d_in, const int* in_sizes, int n_in,
                              void* d_out, int out_size, void* d_ws, size_t ws_size,
                              hipStream_t stream)
{
  const float* images    = (const float*)d_in[0];
  const float* patch_w   = (const float*)d_in[1];
  const float* patch_b   = (const float*)d_in[2];
  const float* cls_token = (const float*)d_in[3];
  const float* pos_embed = (const float*)d_in[4];
  const float* ln1_w = (const float*)d_in[5];
  const float* ln1_b = (const float*)d_in[6];
  const float* qkv_w = (const float*)d_in[7];
  const float* qkv_b = (const float*)d_in[8];
  const float* proj_w = (const float*)d_in[9];
  const float* proj_b = (const float*)d_in[10];
  const float* ln2_w = (const float*)d_in[11];
  const float* ln2_b = (const float*)d_in[12];
  const float* fc1_w = (const float*)d_in[13];
  const float* fc1_b = (const float*)d_in[14];
  const float* fc2_w = (const float*)d_in[15];
  const float* fc2_b = (const float*)d_in[16];
  const float* norm_w = (const float*)d_in[17];
  const float* norm_b = (const float*)d_in[18];
  const float* head_w = (const float*)d_in[19];
  const float* head_b = (const float*)d_in[20];

  char* ws = (char*)d_ws;
  size_t off = 0;
  auto alloc = [&](size_t bytes) { void* p = ws + off; off += (bytes + 255) & ~(size_t)255; return p; };
  float* x            = (float*)alloc((size_t)MTOK * DIM * 4);
  float* xc           = (float*)alloc((size_t)MCTOK * DIM * 4);
  unsigned short* xn  = (unsigned short*)alloc((size_t)MTOK * DIM * 2);
  // shared region: h1 (fc1 out / im2col) overlaid with q/k/v (disjoint in time)
  size_t h1_bytes = (size_t)MTOK * MLPD * 2;
  unsigned short* h1  = (unsigned short*)alloc(h1_bytes);
  unsigned short* qb  = h1;
  unsigned short* kb  = qb + (size_t)BATCH * NH * SQ * HDIM;
  unsigned short* vb  = kb + (size_t)BATCH * NH * SQ * HDIM;
  size_t vbytes = (size_t)BATCH * NH * HDIM * VLDF * 2;
  unsigned short* lncls = (unsigned short*)alloc((size_t)64 * DIM * 2);
  float* norms = (float*)alloc((size_t)MTOK * 4);
  short* sidx  = (short*)alloc((size_t)MCTOK * 2);
  int* cnt = (int*)alloc(BATCH * 4);
  // bf16 weight caches
  size_t n_qkvw = (size_t)12 * 2304 * DIM, n_projw = (size_t)12 * DIM * DIM;
  size_t n_fc1w = (size_t)12 * MLPD * DIM, n_fc2w = (size_t)12 * DIM * MLPD;
  size_t n_patw = (size_t)DIM * DIM, n_headw = (size_t)1000 * DIM;
  unsigned short* wqkv = (unsigned short*)alloc(n_qkvw * 2);
  unsigned short* wproj = (unsigned short*)alloc(n_projw * 2);
  unsigned short* wfc1 = (unsigned short*)alloc(n_fc1w * 2);
  unsigned short* wfc2 = (unsigned short*)alloc(n_fc2w * 2);
  unsigned short* wpat = (unsigned short*)alloc(n_patw * 2);
  unsigned short* whead = (unsigned short*)alloc(n_headw * 2);
  const bool usebf = (off <= ws_size);

  hipMemsetAsync(vb, 0, vbytes, stream);  // finite bytes in V pad cols

  if (usebf) {
    cvt_kernel<<<(int)((n_qkvw/8 + 255)/256), 256, 0, stream>>>(qkv_w, wqkv, (int)(n_qkvw/8));
    cvt_kernel<<<(int)((n_projw/8 + 255)/256), 256, 0, stream>>>(proj_w, wproj, (int)(n_projw/8));
    cvt_kernel<<<(int)((n_fc1w/8 + 255)/256), 256, 0, stream>>>(fc1_w, wfc1, (int)(n_fc1w/8));
    cvt_kernel<<<(int)((n_fc2w/8 + 255)/256), 256, 0, stream>>>(fc2_w, wfc2, (int)(n_fc2w/8));
    cvt_kernel<<<(int)((n_patw/8 + 255)/256), 256, 0, stream>>>(patch_w, wpat, (int)(n_patw/8));
    cvt_kernel<<<(int)((n_headw/8 + 255)/256), 256, 0, stream>>>(head_w, whead, (int)(n_headw/8));
  }

  // patch embed (im2col into h1; disjoint from vb region use)
  im2col_kernel<<<4704, 256, 0, stream>>>(images, h1);
  launch_gemm<EPI_PATCH, 64>(stream, usebf, h1, DIM, patch_w, wpat, DIM,
      patch_b, 12544, DIM, DIM, x, pos_embed, nullptr, nullptr, nullptr, nullptr, nullptr);
  clspos_kernel<<<192, 256, 0, stream>>>(cls_token, pos_embed, x);

  // layers 0..3: full 197 tokens
  for (int l = 0; l < 4; ++l) {
    ln_kernel<<<MTOK, 256, 0, stream>>>(x, DIM, ln1_w + l * DIM, ln1_b + l * DIM, xn);
    launch_gemm256<EPI_QKV>(stream, usebf, xn, DIM,
        qkv_w + (size_t)l * 2304 * DIM, wqkv + (size_t)l * 2304 * DIM, DIM,
        qkv_b + l * 2304, MTOK, 2304, DIM, nullptr, qb, kb, vb);
    attn_kernel<13, SQ, VLDF, 248, false><<<BATCH * NH, 256, 0, stream>>>(qb, kb, vb, nullptr, xn);
    launch_gemm<EPI_RESID, 64>(stream, usebf, xn, DIM,
        proj_w + (size_t)l * DIM * DIM, wproj + (size_t)l * DIM * DIM, DIM,
        proj_b + l * DIM, MTOK, DIM, DIM, x, nullptr, nullptr, nullptr, nullptr, nullptr, nullptr);
    ln_kernel<<<MTOK, 256, 0, stream>>>(x, DIM, ln2_w + l * DIM, ln2_b + l * DIM, xn);
    launch_gemm256<EPI_GELU>(stream, usebf, xn, DIM,
        fc1_w + (size_t)l * MLPD * DIM, wfc1 + (size_t)l * MLPD * DIM, DIM,
        fc1_b + l * MLPD, MTOK, MLPD, DIM, h1, nullptr, nullptr, nullptr);
    launch_gemm<EPI_RESID, 64>(stream, usebf, h1, MLPD,
        fc2_w + (size_t)l * DIM * MLPD, wfc2 + (size_t)l * DIM * MLPD, MLPD,
        fc2_b + l * DIM, MTOK, DIM, MLPD, x, nullptr, nullptr, nullptr, nullptr, nullptr, nullptr);
  }

  // prune: top-98 by norm (+cls), compact to 100 slots/image
  norms_kernel<<<(MTOK + 3) / 4, 256, 0, stream>>>(x, norms);
  topk_select<<<BATCH, 256, 0, stream>>>(norms, sidx, cnt);
  gather_kernel<<<MCTOK, 192, 0, stream>>>(x, sidx, xc);

  // layers 4..11: compact tokens, key mask = slot < cnt[b]
  for (int l = 4; l < 12; ++l) {
    ln_kernel<<<MCTOK, 256, 0, stream>>>(xc, DIM, ln1_w + l * DIM, ln1_b + l * DIM, xn);
    launch_gemm256<EPI_QKVC>(stream, usebf, xn, DIM,
        qkv_w + (size_t)l * 2304 * DIM, wqkv + (size_t)l * 2304 * DIM, DIM,
        qkv_b + l * 2304, MCTOK, 2304, DIM, nullptr, qb, kb, vb);
    attn_kernel<7, CSLOT, VLDC, 136, true><<<BATCH * NH, 256, 0, stream>>>(qb, kb, vb, cnt, xn);
    launch_gemm<EPI_RESID, 64>(stream, usebf, xn, DIM,
        proj_w + (size_t)l * DIM * DIM, wproj + (size_t)l * DIM * DIM, DIM,
        proj_b + l * DIM, MCTOK, DIM, DIM, xc, nullptr, nullptr, nullptr, nullptr, nullptr, nullptr);
    ln_kernel<<<MCTOK, 256, 0, stream>>>(xc, DIM, ln2_w + l * DIM, ln2_b + l * DIM, xn);
    launch_gemm256<EPI_GELU>(stream, usebf, xn, DIM,
        fc1_w + (size_t)l * MLPD * DIM, wfc1 + (size_t)l * MLPD * DIM, DIM,
        fc1_b + l * MLPD, MCTOK, MLPD, DIM, h1, nullptr, nullptr, nullptr);
    launch_gemm<EPI_RESID, 64>(stream, usebf, h1, MLPD,
        fc2_w + (size_t)l * DIM * MLPD, wfc2 + (size_t)l * DIM * MLPD, MLPD,
        fc2_b + l * DIM, MCTOK, DIM, MLPD, xc, nullptr, nullptr, nullptr, nullptr, nullptr, nullptr);
  }

  ln_kernel<<<64, 256, 0, stream>>>(xc, (long long)CSLOT * DIM, norm_w, norm_b, lncls);
  launch_gemm<EPI_HEAD, 64>(stream, usebf, lncls, DIM, head_w, whead, DIM,
      head_b, 64, 1000, DIM, nullptr, nullptr, nullptr, nullptr, nullptr, nullptr, (float*)d_out);
  (void)in_sizes; (void)n_in; (void)out_size;
}

// Round 8
// 3696.667 us; speedup vs baseline: 1.0200x; 1.0200x over previous
//
#include <hip/hip_runtime.h>
#include <hip/hip_bf16.h>
#include <cstdint>

#define NH 12
#define SQ 197
#define DIM 768
#define HDIM 64
#define BATCH 64
#define MTOK (BATCH*SQ)   // 12608
#define MLPD 3072
#define NKEEP 98
#define CSLOT 100         // compact slots per image (98/99 kept + pad)
#define MCTOK (BATCH*CSLOT) // 6400
#define VLDF 224          // padded V cols, full mode (7*32)
#define VLDC 128          // padded V cols, compact mode (4*32)

typedef __attribute__((ext_vector_type(8))) short bf16x8;
typedef __attribute__((ext_vector_type(8))) unsigned short ushort8;
typedef __attribute__((ext_vector_type(4))) unsigned short ushort4v;
typedef __attribute__((ext_vector_type(4))) float floatx4;

// Native RTNE f32->bf16 (compiler emits v_cvt_pk_bf16_f32 for pairs, m240).
__device__ __forceinline__ unsigned short f2bf(float f) {
  __hip_bfloat16 h = __float2bfloat16(f);
  return reinterpret_cast<unsigned short&>(h);
}

// A&S 7.1.26 erf: |err| <= 1.5e-7 (<< bf16 ulp), ~12 VALU ops vs ~30+ libm.
__device__ __forceinline__ float erf_fast(float x) {
  float ax = fabsf(x);
  float t = 1.f / (1.f + 0.3275911f * ax);
  float y = t * (0.254829592f + t * (-0.284496736f + t * (1.421413741f +
            t * (-1.453152027f + t * 1.061405429f))));
  float r = 1.f - y * __expf(-ax * ax);
  return copysignf(r, x);
}

// async global->LDS, 16B per lane. LDS dest is wave-uniform base + lane*16.
__device__ __forceinline__ void gload16(const unsigned short* g, unsigned short* l) {
  __builtin_amdgcn_global_load_lds(
      (const __attribute__((address_space(1))) void*)g,
      (__attribute__((address_space(3))) void*)l, 16, 0, 0);
}

enum { EPI_PATCH = 0, EPI_QKV = 1, EPI_RESID = 2, EPI_GELU = 3, EPI_HEAD = 4, EPI_QKVC = 5 };

// Shared epilogue. C/D layout col=lane&15, row=(lane>>4)*4+j [verified m89/m91]
template<int EPI, bool CHK, int MR, int NR>
__device__ __forceinline__ void gemm_epilogue(
    floatx4 (&acc)[MR][NR], int m0, int n0, int wr, int wc, int l15, int l4,
    const float* __restrict__ bias, int M, int N,
    float* __restrict__ xresid, const float* __restrict__ pos,
    unsigned short* __restrict__ obf, unsigned short* __restrict__ qb,
    unsigned short* __restrict__ kb, unsigned short* __restrict__ vb,
    float* __restrict__ ofp)
{
#pragma unroll
  for (int mr = 0; mr < MR; ++mr) {
#pragma unroll
    for (int nr = 0; nr < NR; ++nr) {
#pragma unroll
      for (int j = 0; j < 4; ++j) {
        int m = m0 + wr + mr * 16 + l4 * 4 + j;
        int n = n0 + wc + nr * 16 + l15;
        if (CHK && (m >= M || n >= N)) continue;
        float val = acc[mr][nr][j] + bias[n];
        if constexpr (EPI == EPI_PATCH) {
          int b = m / 196, p = m - b * 196;
          xresid[(size_t)(b * SQ + 1 + p) * DIM + n] = val + pos[(1 + p) * DIM + n];
        } else if constexpr (EPI == EPI_QKV || EPI == EPI_QKVC) {
          constexpr int SR = (EPI == EPI_QKV) ? SQ : CSLOT;
          constexpr int VL = (EPI == EPI_QKV) ? VLDF : VLDC;
          int part = n / DIM; int within = n - part * DIM;
          int h = within >> 6, hd = within & 63;
          int b = m / SR, s = m - b * SR;
          if (part == 0)      qb[(((size_t)(b * NH + h)) * SR + s) * HDIM + hd] = f2bf(val * 0.125f);
          else if (part == 1) kb[(((size_t)(b * NH + h)) * SR + s) * HDIM + hd] = f2bf(val);
          else                vb[(((size_t)(b * NH + h)) * HDIM + hd) * VL + s] = f2bf(val);
        } else if constexpr (EPI == EPI_RESID) {
          xresid[(size_t)m * DIM + n] += val;
        } else if constexpr (EPI == EPI_GELU) {
          float g = 0.5f * val * (1.f + erf_fast(val * 0.70710678118654752f));
          obf[(size_t)m * MLPD + n] = f2bf(g);
        } else {
          ofp[(size_t)m * 1000 + n] = val;
        }
      }
    }
  }
}

// ------------------------------- GEMM 256x256, 8 waves, 2-phase ----------
// Used ONLY for full-mode qkv/fc1 (grids 450/600 blocks). LDS 128 KiB ->
// 1 block/CU; the counted-vmcnt 2-phase provides the only latency overlap,
// so this wins over 128-tile only when the grid covers all CUs (r7 lesson:
// compact grids of 225-300 blocks REGRESS here -> they use the 128-tile).
template<int EPI>
__global__ __launch_bounds__(512, 1)
void gemm_bf256(const unsigned short* __restrict__ A, int lda,
                const unsigned short* __restrict__ Wb, int ldw,
                const float* __restrict__ bias,
                int M, int N, int K,
                float* __restrict__ xresid,
                const float* __restrict__ pos,
                unsigned short* __restrict__ obf,
                unsigned short* __restrict__ qb,
                unsigned short* __restrict__ kb,
                unsigned short* __restrict__ vb,
                float* __restrict__ ofp)
{
  __shared__ unsigned short As[2][256 * 64];   // 64 KiB
  __shared__ unsigned short Bs[2][256 * 64];   // 64 KiB
  const int tid = threadIdx.x;
  const int lane = tid & 63;
  const int w = tid >> 6;               // 0..7
  const int wr = (w >> 2) * 128;        // 2 M-waves
  const int wc = (w & 3) * 64;          // 4 N-waves

  // T1 bijective XCD swizzle (m204)
  const int gx = gridDim.x;
  const int nwg = gx * gridDim.y;
  const int orig = blockIdx.y * gx + blockIdx.x;
  const int q = nwg >> 3, r = nwg & 7;
  const int xcd = orig & 7, o8 = orig >> 3;
  const int wgid = ((xcd < r) ? xcd * (q + 1) : r * (q + 1) + (xcd - r) * q) + o8;
  const int bx = wgid % gx, by = wgid / gx;
  const int m0 = by * 256, n0 = bx * 256;
  const int l15 = lane & 15, l4 = lane >> 4;

  // staging: waves 0-3 load A, waves 4-7 load B; 8 groups of 8 rows/wave.
  // pre-swizzled source chunk = sub ^ rsub (row&7 == rsub for 8-row groups).
  const int sub = lane & 7, rsub = lane >> 3;
  const int scol = ((sub ^ rsub) << 3);
  const bool isA = (w < 4);
  const unsigned short* gp[8];
  int ldst[8];
#pragma unroll
  for (int j = 0; j < 8; ++j) {
    int row = (w & 3) * 64 + j * 8 + rsub;          // row within 256-tile
    if (isA) {
      int ra = m0 + row; if (ra > M - 1) ra = M - 1;
      gp[j] = A + (size_t)ra * lda + scol;
    } else {
      int rb = n0 + row; if (rb > N - 1) rb = N - 1;
      gp[j] = Wb + (size_t)rb * ldw + scol;
    }
    ldst[j] = ((w & 3) * 8 + j) * 512;              // short offset in buffer
  }

  floatx4 acc[8][4];
#pragma unroll
  for (int i = 0; i < 8; ++i)
#pragma unroll
    for (int j = 0; j < 4; ++j) acc[i][j] = {0.f, 0.f, 0.f, 0.f};

  auto STAGE = [&](int buf, int kt) {
    unsigned short* base = isA ? &As[buf][0] : &Bs[buf][0];
#pragma unroll
    for (int j = 0; j < 8; ++j)
      gload16(gp[j] + kt, base + ldst[j]);
  };

  const int nk = K >> 6;
  STAGE(0, 0);                 // 8 loads/lane in flight
  int cur = 0;
  for (int ki = 0; ki < nk; ++ki) {
    if (ki + 1 < nk) {
      STAGE(cur ^ 1, (ki + 1) << 6);                    // 16 in flight
      asm volatile("s_waitcnt vmcnt(8)" ::: "memory");  // cur's 8 landed
    } else {
      asm volatile("s_waitcnt vmcnt(0)" ::: "memory");
    }
    __builtin_amdgcn_sched_barrier(0);
    __builtin_amdgcn_s_barrier();            // tile[cur] visible to all waves
    const unsigned short* Ac = &As[cur][0];
    const unsigned short* Bc = &Bs[cur][0];
#pragma unroll
    for (int kk = 0; kk < 2; ++kk) {
      bf16x8 af[8], bfr[4];
#pragma unroll
      for (int mr = 0; mr < 8; ++mr) {
        int row = wr + mr * 16 + l15;
        int cs = (kk * 4 + l4) ^ (row & 7);
        af[mr] = *(const bf16x8*)&Ac[row * 64 + cs * 8];
      }
#pragma unroll
      for (int nr = 0; nr < 4; ++nr) {
        int row = wc + nr * 16 + l15;
        int cs = (kk * 4 + l4) ^ (row & 7);
        bfr[nr] = *(const bf16x8*)&Bc[row * 64 + cs * 8];
      }
#pragma unroll
      for (int mr = 0; mr < 8; ++mr)
#pragma unroll
        for (int nr = 0; nr < 4; ++nr)
          acc[mr][nr] = __builtin_amdgcn_mfma_f32_16x16x32_bf16(af[mr], bfr[nr], acc[mr][nr], 0, 0, 0);
    }
    __builtin_amdgcn_sched_barrier(0);
    __builtin_amdgcn_s_barrier();            // all waves done reading tile[cur]
    cur ^= 1;
  }
  if (m0 + 256 <= M && n0 + 256 <= N)
    gemm_epilogue<EPI, false, 8, 4>(acc, m0, n0, wr, wc, l15, l4, bias, M, N,
                                    xresid, pos, obf, qb, kb, vb, ofp);
  else
    gemm_epilogue<EPI, true, 8, 4>(acc, m0, n0, wr, wc, l15, l4, bias, M, N,
                                   xresid, pos, obf, qb, kb, vb, ofp);
}

// --------------------------------- GEMM 128xBN, 4 waves, 1-phase ---------
// High-occupancy workhorse (24-32 KiB LDS, 5-6 blocks/CU): compact-layer
// qkv/fc1 (BN=128) and all N=768-class GEMMs (BN=64).
template<int EPI, int BN>
__global__ __launch_bounds__(256)
void gemm_bf(const unsigned short* __restrict__ A, int lda,
             const unsigned short* __restrict__ Wb, int ldw,
             const float* __restrict__ bias,
             int M, int N, int K,
             float* __restrict__ xresid,
             const float* __restrict__ pos,
             unsigned short* __restrict__ obf,
             unsigned short* __restrict__ qb,
             unsigned short* __restrict__ kb,
             unsigned short* __restrict__ vb,
             float* __restrict__ ofp)
{
  constexpr int NR = BN / 32;
  constexpr int NG = (128 + BN) / 8;
  constexpr int PG = NG / 4;
  __shared__ unsigned short As[128 * 64];
  __shared__ unsigned short Bs[BN * 64];
  const int tid = threadIdx.x;
  const int lane = tid & 63;
  const int w = tid >> 6;
  const int wr = (w >> 1) * 64, wc = (w & 1) * (BN / 2);

  const int gx = gridDim.x;
  const int nwg = gx * gridDim.y;
  const int orig = blockIdx.y * gx + blockIdx.x;
  const int q = nwg >> 3, r = nwg & 7;
  const int xcd = orig & 7, o8 = orig >> 3;
  const int wgid = ((xcd < r) ? xcd * (q + 1) : r * (q + 1) + (xcd - r) * q) + o8;
  const int bx = wgid % gx, by = wgid / gx;
  const int m0 = by * 128, n0 = bx * BN;
  const int l15 = lane & 15, l4 = lane >> 4;

  const int sub = lane & 7, rsub = lane >> 3;
  const int scol = ((sub ^ rsub) << 3);
  const unsigned short* gp[PG];
  unsigned short* lp[PG];
#pragma unroll
  for (int j = 0; j < PG; ++j) {
    int t = w * PG + j;
    if (t < 16) {
      int row = t * 8 + rsub;
      int ra = m0 + row; if (ra > M - 1) ra = M - 1;
      gp[j] = A + (size_t)ra * lda + scol;
      lp[j] = &As[t * 512];
    } else {
      int tb = t - 16;
      int row = tb * 8 + rsub;
      int rb = n0 + row; if (rb > N - 1) rb = N - 1;
      gp[j] = Wb + (size_t)rb * ldw + scol;
      lp[j] = &Bs[tb * 512];
    }
  }

  floatx4 acc[4][NR];
#pragma unroll
  for (int i = 0; i < 4; ++i)
#pragma unroll
    for (int j = 0; j < NR; ++j) acc[i][j] = {0.f, 0.f, 0.f, 0.f};

  for (int kt = 0; kt < K; kt += 64) {
#pragma unroll
    for (int j = 0; j < PG; ++j)
      gload16(gp[j] + kt, lp[j]);
    __syncthreads();
#pragma unroll
    for (int kk = 0; kk < 2; ++kk) {
      bf16x8 af[4], bfr[NR];
#pragma unroll
      for (int mr = 0; mr < 4; ++mr) {
        int row = wr + mr * 16 + l15;
        int cs = (kk * 4 + l4) ^ (row & 7);
        af[mr] = *(const bf16x8*)&As[row * 64 + cs * 8];
      }
#pragma unroll
      for (int nr = 0; nr < NR; ++nr) {
        int row = wc + nr * 16 + l15;
        int cs = (kk * 4 + l4) ^ (row & 7);
        bfr[nr] = *(const bf16x8*)&Bs[row * 64 + cs * 8];
      }
#pragma unroll
      for (int mr = 0; mr < 4; ++mr)
#pragma unroll
        for (int nr = 0; nr < NR; ++nr)
          acc[mr][nr] = __builtin_amdgcn_mfma_f32_16x16x32_bf16(af[mr], bfr[nr], acc[mr][nr], 0, 0, 0);
    }
    __syncthreads();
  }
  if (m0 + 128 <= M && n0 + BN <= N)
    gemm_epilogue<EPI, false, 4, NR>(acc, m0, n0, wr, wc, l15, l4, bias, M, N,
                                     xresid, pos, obf, qb, kb, vb, ofp);
  else
    gemm_epilogue<EPI, true, 4, NR>(acc, m0, n0, wr, wc, l15, l4, bias, M, N,
                                    xresid, pos, obf, qb, kb, vb, ofp);
}

// ------------------------------------- GEMM, f32 W (fallback, reg-staged) --
template<int EPI>
__global__ __launch_bounds__(256)
void gemm_f32(const unsigned short* __restrict__ A, int lda,
              const float* __restrict__ Wf, int ldw,
              const float* __restrict__ bias,
              int M, int N, int K,
              float* __restrict__ xresid,
              const float* __restrict__ pos,
              unsigned short* __restrict__ obf,
              unsigned short* __restrict__ qb,
              unsigned short* __restrict__ kb,
              unsigned short* __restrict__ vb,
              float* __restrict__ ofp)
{
  __shared__ unsigned short As[128 * 64];
  __shared__ unsigned short Bs[128 * 64];
  const int tid = threadIdx.x;
  const int lane = tid & 63;
  const int w = tid >> 6;
  const int wr = (w >> 1) * 64, wc = (w & 1) * 64;
  const int m0 = blockIdx.y * 128, n0 = blockIdx.x * 128;
  const int l15 = lane & 15, l4 = lane >> 4;

  floatx4 acc[4][4];
#pragma unroll
  for (int i = 0; i < 4; ++i)
#pragma unroll
    for (int j = 0; j < 4; ++j) acc[i][j] = {0.f, 0.f, 0.f, 0.f};

  for (int kt = 0; kt < K; kt += 64) {
#pragma unroll
    for (int i = 0; i < 4; ++i) {
      int g = tid + 256 * i;
      int row = g >> 3, c = g & 7;
      int sw = (c ^ (row & 7)) * 8;
      int ra = m0 + row; if (ra > M - 1) ra = M - 1;
      ushort8 av = *(const ushort8*)(A + (size_t)ra * lda + kt + c * 8);
      *(ushort8*)&As[row * 64 + sw] = av;
      int rb = n0 + row; if (rb > N - 1) rb = N - 1;
      const float* bs = Wf + (size_t)rb * ldw + kt + c * 8;
      float4 f0 = *(const float4*)bs;
      float4 f1 = *(const float4*)(bs + 4);
      ushort8 bv;
      bv[0] = f2bf(f0.x); bv[1] = f2bf(f0.y); bv[2] = f2bf(f0.z); bv[3] = f2bf(f0.w);
      bv[4] = f2bf(f1.x); bv[5] = f2bf(f1.y); bv[6] = f2bf(f1.z); bv[7] = f2bf(f1.w);
      *(ushort8*)&Bs[row * 64 + sw] = bv;
    }
    __syncthreads();
#pragma unroll
    for (int kk = 0; kk < 2; ++kk) {
      bf16x8 af[4], bfr[4];
#pragma unroll
      for (int mr = 0; mr < 4; ++mr) {
        int row = wr + mr * 16 + l15;
        int cs = (kk * 4 + l4) ^ (row & 7);
        af[mr] = *(const bf16x8*)&As[row * 64 + cs * 8];
      }
#pragma unroll
      for (int nr = 0; nr < 4; ++nr) {
        int row = wc + nr * 16 + l15;
        int cs = (kk * 4 + l4) ^ (row & 7);
        bfr[nr] = *(const bf16x8*)&Bs[row * 64 + cs * 8];
      }
#pragma unroll
      for (int mr = 0; mr < 4; ++mr)
#pragma unroll
        for (int nr = 0; nr < 4; ++nr)
          acc[mr][nr] = __builtin_amdgcn_mfma_f32_16x16x32_bf16(af[mr], bfr[nr], acc[mr][nr], 0, 0, 0);
    }
    __syncthreads();
  }
  if (m0 + 128 <= M && n0 + 128 <= N)
    gemm_epilogue<EPI, false, 4, 4>(acc, m0, n0, wr, wc, l15, l4, bias, M, N,
                                    xresid, pos, obf, qb, kb, vb, ofp);
  else
    gemm_epilogue<EPI, true, 4, 4>(acc, m0, n0, wr, wc, l15, l4, bias, M, N,
                                   xresid, pos, obf, qb, kb, vb, ofp);
}

// ------------------------------------------------------- weight convert --
__global__ __launch_bounds__(256)
void cvt_kernel(const float* __restrict__ src, unsigned short* __restrict__ dst, int nchunks)
{
  int i = blockIdx.x * 256 + threadIdx.x;
  if (i >= nchunks) return;
  float4 f0 = *(const float4*)(src + (size_t)i * 8);
  float4 f1 = *(const float4*)(src + (size_t)i * 8 + 4);
  ushort8 v;
  v[0] = f2bf(f0.x); v[1] = f2bf(f0.y); v[2] = f2bf(f0.z); v[3] = f2bf(f0.w);
  v[4] = f2bf(f1.x); v[5] = f2bf(f1.y); v[6] = f2bf(f1.z); v[7] = f2bf(f1.w);
  *(ushort8*)(dst + (size_t)i * 8) = v;
}

// ------------------------------------------------------------- LayerNorm --
// 192 threads x float4 (16B/lane, G13): one row/block, 3-wave reduce.
__global__ __launch_bounds__(192)
void ln_kernel(const float* __restrict__ x, long long row_stride,
               const float* __restrict__ g, const float* __restrict__ b,
               unsigned short* __restrict__ out)
{
  int row = blockIdx.x;
  const float4* xr = (const float4*)(x + (size_t)row * row_stride);
  int t = threadIdx.x;
  float4 v = xr[t];
  float s = v.x + v.y + v.z + v.w;
  float sq = v.x * v.x + v.y * v.y + v.z * v.z + v.w * v.w;
  __shared__ float sb[6];
  for (int o = 32; o; o >>= 1) { s += __shfl_down(s, o); sq += __shfl_down(sq, o); }
  if ((t & 63) == 0) { sb[t >> 6] = s; sb[3 + (t >> 6)] = sq; }
  __syncthreads();
  s = sb[0] + sb[1] + sb[2];
  sq = sb[3] + sb[4] + sb[5];
  float mean = s * (1.f / 768.f);
  float var = sq * (1.f / 768.f) - mean * mean;
  float rstd = rsqrtf(var + 1e-6f);
  float4 gg = ((const float4*)g)[t];
  float4 bb = ((const float4*)b)[t];
  ushort4v o4;
  o4[0] = f2bf((v.x - mean) * rstd * gg.x + bb.x);
  o4[1] = f2bf((v.y - mean) * rstd * gg.y + bb.y);
  o4[2] = f2bf((v.z - mean) * rstd * gg.z + bb.z);
  o4[3] = f2bf((v.w - mean) * rstd * gg.w + bb.w);
  *(ushort4v*)(out + (size_t)row * DIM + t * 4) = o4;
}

// ------------------------------------------------------------- Attention --
template<int NT, int SROWS, int VLD, int PSTR, bool CNT>
__global__ __launch_bounds__(256)
void attn_kernel(const unsigned short* __restrict__ qb,
                 const unsigned short* __restrict__ kb,
                 const unsigned short* __restrict__ vb,
                 const int* __restrict__ cnt,
                 unsigned short* __restrict__ outA)
{
  __shared__ unsigned short Ks[NT * 16 * 64];
  __shared__ unsigned short Ps[4][16 * PSTR];
  int bh = blockIdx.x;
  int b = bh / NH, h = bh - b * NH;
  const int tid = threadIdx.x, lane = tid & 63, w = tid >> 6;
  const int l15 = lane & 15, l4 = lane >> 4;
  const unsigned short* kbase = kb + (size_t)bh * SROWS * HDIM;
  const unsigned short* qbase = qb + (size_t)bh * SROWS * HDIM;
  const unsigned short* vbase = vb + (size_t)bh * HDIM * VLD;
  const int limit = CNT ? cnt[b] : SROWS;

  constexpr int KCH = NT * 16 * 8;
  for (int i = 0; i < (KCH + 255) / 256; ++i) {
    int gch = tid + 256 * i;
    if (gch < KCH) {
      int row = gch >> 3, c = gch & 7;
      int rs = row > SROWS - 1 ? SROWS - 1 : row;
      ushort8 kv = *(const ushort8*)(kbase + (size_t)rs * HDIM + c * 8);
      *(ushort8*)&Ks[row * 64 + ((c ^ (row & 7))) * 8] = kv;
    }
  }
  __syncthreads();

  for (int qt = w; qt < NT; qt += 4) {
    int qrow = qt * 16 + l15; if (qrow > SROWS - 1) qrow = SROWS - 1;
    bf16x8 aq0 = *(const bf16x8*)(qbase + (size_t)qrow * HDIM + l4 * 8);
    bf16x8 aq1 = *(const bf16x8*)(qbase + (size_t)qrow * HDIM + 32 + l4 * 8);

    floatx4 lg[NT];
#pragma unroll
    for (int nt = 0; nt < NT; ++nt) {
      lg[nt] = {0.f, 0.f, 0.f, 0.f};
      int row = nt * 16 + l15;
      int cs0 = (l4) ^ (row & 7);
      int cs1 = (4 + l4) ^ (row & 7);
      bf16x8 bk0 = *(const bf16x8*)&Ks[row * 64 + cs0 * 8];
      bf16x8 bk1 = *(const bf16x8*)&Ks[row * 64 + cs1 * 8];
      lg[nt] = __builtin_amdgcn_mfma_f32_16x16x32_bf16(aq0, bk0, lg[nt], 0, 0, 0);
      lg[nt] = __builtin_amdgcn_mfma_f32_16x16x32_bf16(aq1, bk1, lg[nt], 0, 0, 0);
    }
    float mx[4] = {-1e30f, -1e30f, -1e30f, -1e30f};
#pragma unroll
    for (int nt = 0; nt < NT; ++nt) {
      int col = nt * 16 + l15;
      bool valid = col < limit;
#pragma unroll
      for (int j = 0; j < 4; ++j) {
        float v = valid ? lg[nt][j] : -1e9f;
        lg[nt][j] = v;
        mx[j] = fmaxf(mx[j], v);
      }
    }
#pragma unroll
    for (int j = 0; j < 4; ++j)
      for (int o = 1; o < 16; o <<= 1) mx[j] = fmaxf(mx[j], __shfl_xor(mx[j], o));
    float sm[4] = {0.f, 0.f, 0.f, 0.f};
#pragma unroll
    for (int nt = 0; nt < NT; ++nt)
#pragma unroll
      for (int j = 0; j < 4; ++j) {
        float p = __expf(lg[nt][j] - mx[j]);
        lg[nt][j] = p;
        sm[j] += p;
      }
#pragma unroll
    for (int j = 0; j < 4; ++j) {
      for (int o = 1; o < 16; o <<= 1) sm[j] += __shfl_xor(sm[j], o);
      sm[j] = 1.f / sm[j];
    }
    unsigned short* pw = &Ps[w][0];
#pragma unroll
    for (int nt = 0; nt < NT; ++nt) {
      int col = nt * 16 + l15;
#pragma unroll
      for (int j = 0; j < 4; ++j)
        pw[(l4 * 4 + j) * PSTR + col] = f2bf(lg[nt][j]);
    }
#pragma unroll
    for (int j = 0; j < 4; ++j)
      pw[(l4 * 4 + j) * PSTR + NT * 16 + l15] = 0;
    floatx4 oacc[4];
#pragma unroll
    for (int nr = 0; nr < 4; ++nr) oacc[nr] = {0.f, 0.f, 0.f, 0.f};
#pragma unroll
    for (int ks = 0; ks < VLD / 32; ++ks) {
      bf16x8 ap = *(const bf16x8*)&pw[l15 * PSTR + ks * 32 + l4 * 8];
#pragma unroll
      for (int nr = 0; nr < 4; ++nr) {
        bf16x8 bv = *(const bf16x8*)(vbase + (size_t)(nr * 16 + l15) * VLD + ks * 32 + l4 * 8);
        oacc[nr] = __builtin_amdgcn_mfma_f32_16x16x32_bf16(ap, bv, oacc[nr], 0, 0, 0);
      }
    }
#pragma unroll
    for (int nr = 0; nr < 4; ++nr)
#pragma unroll
      for (int j = 0; j < 4; ++j) {
        int qi = qt * 16 + l4 * 4 + j;
        if (qi < SROWS)
          outA[((size_t)(b * SROWS + qi)) * DIM + h * HDIM + nr * 16 + l15] = f2bf(oacc[nr][j] * sm[j]);
      }
  }
}

// ---------------------------------------------------------------- im2col --
__global__ __launch_bounds__(256)
void im2col_kernel(const float* __restrict__ images, unsigned short* __restrict__ out)
{
  int idx = blockIdx.x * 256 + threadIdx.x;
  int token = idx / 96;
  int kc = (idx - token * 96) * 8;
  int b = token / 196, p = token - b * 196;
  int py = p / 14, px = p - py * 14;
  int c = kc >> 8, rem = kc & 255;
  int i = rem >> 4, j0 = rem & 15;
  const float* src = images + (((size_t)(b * 3 + c) * 224 + py * 16 + i) * 224 + px * 16 + j0);
  float4 f0 = *(const float4*)src;
  float4 f1 = *(const float4*)(src + 4);
  ushort8 v;
  v[0] = f2bf(f0.x); v[1] = f2bf(f0.y); v[2] = f2bf(f0.z); v[3] = f2bf(f0.w);
  v[4] = f2bf(f1.x); v[5] = f2bf(f1.y); v[6] = f2bf(f1.z); v[7] = f2bf(f1.w);
  *(ushort8*)(out + (size_t)token * DIM + kc) = v;
}

__global__ __launch_bounds__(256)
void clspos_kernel(const float* __restrict__ cls, const float* __restrict__ pos,
                   float* __restrict__ x)
{
  int idx = blockIdx.x * 256 + threadIdx.x;
  int b = idx / DIM, d = idx - b * DIM;
  x[(size_t)(b * SQ) * DIM + d] = cls[d] + pos[d];
}

// ----------------------------------------------- top-k (3 parallel stages) --
__global__ __launch_bounds__(256)
void norms_kernel(const float* __restrict__ x, float* __restrict__ norms)
{
  int row = blockIdx.x * 4 + (threadIdx.x >> 6);
  if (row >= MTOK) return;
  int lane = threadIdx.x & 63;
  const float* xr = x + (size_t)row * DIM;
  float acc = 0.f;
  for (int d = lane; d < DIM; d += 64) { float v = xr[d]; acc += v * v; }
  for (int o = 32; o; o >>= 1) acc += __shfl_down(acc, o);
  if (lane == 0) norms[row] = acc;
}

// Rank-count selection == jax.lax.top_k (desc, stable ties -> lower index).
__global__ __launch_bounds__(256)
void topk_select(const float* __restrict__ norms, short* __restrict__ sidx,
                 int* __restrict__ cntg)
{
  int b = blockIdx.x;
  __shared__ float sc[SQ];
  __shared__ unsigned char keep[SQ];
  int tid = threadIdx.x;
  if (tid < SQ) sc[tid] = norms[b * SQ + tid];
  __syncthreads();
  if (tid < SQ) {
    float mine = sc[tid];
    int rank = 0;
    for (int j = 0; j < SQ; ++j) {
      float v = sc[j];
      rank += (v > mine) || (v == mine && j < tid);
    }
    keep[tid] = (rank < NKEEP) || (tid == 0);
  }
  __syncthreads();
  if (tid == 0) {
    short* row = sidx + b * CSLOT;
    int c = 0;
    for (int s = 0; s < SQ; ++s) if (keep[s]) row[c++] = (short)s;
    cntg[b] = c;
    for (int s = c; s < CSLOT; ++s) row[s] = 0;  // pad slots copy row 0
  }
}

__global__ __launch_bounds__(192)
void gather_kernel(const float* __restrict__ x, const short* __restrict__ sidx,
                   float* __restrict__ xc)
{
  int g = blockIdx.x;              // b*CSLOT + slot
  int b = g / CSLOT;
  int src = sidx[g];
  const float4* sp = (const float4*)(x + ((size_t)(b * SQ + src)) * DIM);
  float4* dp = (float4*)(xc + (size_t)g * DIM);
  dp[threadIdx.x] = sp[threadIdx.x];
}

// ------------------------------------------------------------------ host --
template<int EPI, int BN>
static inline void launch_gemm(hipStream_t stream, bool usebf,
                               const unsigned short* A, int lda,
                               const float* Wf, const unsigned short* Wb, int ldw,
                               const float* bias, int M, int N, int K,
                               float* xresid, const float* pos,
                               unsigned short* obf, unsigned short* qb,
                               unsigned short* kb, unsigned short* vb, float* ofp)
{
  if (usebf) {
    dim3 grid((N + BN - 1) / BN, (M + 127) / 128);
    gemm_bf<EPI, BN><<<grid, 256, 0, stream>>>(A, lda, Wb, ldw, bias,
        M, N, K, xresid, pos, obf, qb, kb, vb, ofp);
  } else {
    dim3 grid((N + 127) / 128, (M + 127) / 128);
    gemm_f32<EPI><<<grid, 256, 0, stream>>>(A, lda, Wf, ldw, bias,
        M, N, K, xresid, pos, obf, qb, kb, vb, ofp);
  }
}

template<int EPI>
static inline void launch_gemm256(hipStream_t stream, bool usebf,
                                  const unsigned short* A, int lda,
                                  const float* Wf, const unsigned short* Wb, int ldw,
                                  const float* bias, int M, int N, int K,
                                  unsigned short* obf, unsigned short* qb,
                                  unsigned short* kb, unsigned short* vb)
{
  if (usebf) {
    dim3 grid(N / 256, (M + 255) / 256);
    gemm_bf256<EPI><<<grid, 512, 0, stream>>>(A, lda, Wb, ldw, bias,
        M, N, K, nullptr, nullptr, obf, qb, kb, vb, nullptr);
  } else {
    dim3 grid((N + 127) / 128, (M + 127) / 128);
    gemm_f32<EPI><<<grid, 256, 0, stream>>>(A, lda, Wf, ldw, bias,
        M, N, K, nullptr, nullptr, obf, qb, kb, vb, nullptr);
  }
}

extern "C" void kernel_launch(void* const* d_in, const int* in_sizes, int n_in,
                              void* d_out, int out_size, void* d_ws, size_t ws_size,
                              hipStream_t stream)
{
  const float* images    = (const float*)d_in[0];
  const float* patch_w   = (const float*)d_in[1];
  const float* patch_b   = (const float*)d_in[2];
  const float* cls_token = (const float*)d_in[3];
  const float* pos_embed = (const float*)d_in[4];
  const float* ln1_w = (const float*)d_in[5];
  const float* ln1_b = (const float*)d_in[6];
  const float* qkv_w = (const float*)d_in[7];
  const float* qkv_b = (const float*)d_in[8];
  const float* proj_w = (const float*)d_in[9];
  const float* proj_b = (const float*)d_in[10];
  const float* ln2_w = (const float*)d_in[11];
  const float* ln2_b = (const float*)d_in[12];
  const float* fc1_w = (const float*)d_in[13];
  const float* fc1_b = (const float*)d_in[14];
  const float* fc2_w = (const float*)d_in[15];
  const float* fc2_b = (const float*)d_in[16];
  const float* norm_w = (const float*)d_in[17];
  const float* norm_b = (const float*)d_in[18];
  const float* head_w = (const float*)d_in[19];
  const float* head_b = (const float*)d_in[20];

  char* ws = (char*)d_ws;
  size_t off = 0;
  auto alloc = [&](size_t bytes) { void* p = ws + off; off += (bytes + 255) & ~(size_t)255; return p; };
  float* x            = (float*)alloc((size_t)MTOK * DIM * 4);
  float* xc           = (float*)alloc((size_t)MCTOK * DIM * 4);
  unsigned short* xn  = (unsigned short*)alloc((size_t)MTOK * DIM * 2);
  // shared region: h1 (fc1 out / im2col) overlaid with q/k/v (disjoint in time)
  size_t h1_bytes = (size_t)MTOK * MLPD * 2;
  unsigned short* h1  = (unsigned short*)alloc(h1_bytes);
  unsigned short* qb  = h1;
  unsigned short* kb  = qb + (size_t)BATCH * NH * SQ * HDIM;
  unsigned short* vb  = kb + (size_t)BATCH * NH * SQ * HDIM;
  size_t vbytes = (size_t)BATCH * NH * HDIM * VLDF * 2;
  unsigned short* lncls = (unsigned short*)alloc((size_t)64 * DIM * 2);
  float* norms = (float*)alloc((size_t)MTOK * 4);
  short* sidx  = (short*)alloc((size_t)MCTOK * 2);
  int* cnt = (int*)alloc(BATCH * 4);
  // bf16 weight caches
  size_t n_qkvw = (size_t)12 * 2304 * DIM, n_projw = (size_t)12 * DIM * DIM;
  size_t n_fc1w = (size_t)12 * MLPD * DIM, n_fc2w = (size_t)12 * DIM * MLPD;
  size_t n_patw = (size_t)DIM * DIM, n_headw = (size_t)1000 * DIM;
  unsigned short* wqkv = (unsigned short*)alloc(n_qkvw * 2);
  unsigned short* wproj = (unsigned short*)alloc(n_projw * 2);
  unsigned short* wfc1 = (unsigned short*)alloc(n_fc1w * 2);
  unsigned short* wfc2 = (unsigned short*)alloc(n_fc2w * 2);
  unsigned short* wpat = (unsigned short*)alloc(n_patw * 2);
  unsigned short* whead = (unsigned short*)alloc(n_headw * 2);
  const bool usebf = (off <= ws_size);

  hipMemsetAsync(vb, 0, vbytes, stream);  // finite bytes in V pad cols

  if (usebf) {
    cvt_kernel<<<(int)((n_qkvw/8 + 255)/256), 256, 0, stream>>>(qkv_w, wqkv, (int)(n_qkvw/8));
    cvt_kernel<<<(int)((n_projw/8 + 255)/256), 256, 0, stream>>>(proj_w, wproj, (int)(n_projw/8));
    cvt_kernel<<<(int)((n_fc1w/8 + 255)/256), 256, 0, stream>>>(fc1_w, wfc1, (int)(n_fc1w/8));
    cvt_kernel<<<(int)((n_fc2w/8 + 255)/256), 256, 0, stream>>>(fc2_w, wfc2, (int)(n_fc2w/8));
    cvt_kernel<<<(int)((n_patw/8 + 255)/256), 256, 0, stream>>>(patch_w, wpat, (int)(n_patw/8));
    cvt_kernel<<<(int)((n_headw/8 + 255)/256), 256, 0, stream>>>(head_w, whead, (int)(n_headw/8));
  }

  // patch embed (im2col into h1; disjoint from vb region use)
  im2col_kernel<<<4704, 256, 0, stream>>>(images, h1);
  launch_gemm<EPI_PATCH, 64>(stream, usebf, h1, DIM, patch_w, wpat, DIM,
      patch_b, 12544, DIM, DIM, x, pos_embed, nullptr, nullptr, nullptr, nullptr, nullptr);
  clspos_kernel<<<192, 256, 0, stream>>>(cls_token, pos_embed, x);

  // layers 0..3: full 197 tokens (256-sq 2-phase for qkv/fc1: grids 450/600)
  for (int l = 0; l < 4; ++l) {
    ln_kernel<<<MTOK, 192, 0, stream>>>(x, DIM, ln1_w + l * DIM, ln1_b + l * DIM, xn);
    launch_gemm256<EPI_QKV>(stream, usebf, xn, DIM,
        qkv_w + (size_t)l * 2304 * DIM, wqkv + (size_t)l * 2304 * DIM, DIM,
        qkv_b + l * 2304, MTOK, 2304, DIM, nullptr, qb, kb, vb);
    attn_kernel<13, SQ, VLDF, 248, false><<<BATCH * NH, 256, 0, stream>>>(qb, kb, vb, nullptr, xn);
    launch_gemm<EPI_RESID, 64>(stream, usebf, xn, DIM,
        proj_w + (size_t)l * DIM * DIM, wproj + (size_t)l * DIM * DIM, DIM,
        proj_b + l * DIM, MTOK, DIM, DIM, x, nullptr, nullptr, nullptr, nullptr, nullptr, nullptr);
    ln_kernel<<<MTOK, 192, 0, stream>>>(x, DIM, ln2_w + l * DIM, ln2_b + l * DIM, xn);
    launch_gemm256<EPI_GELU>(stream, usebf, xn, DIM,
        fc1_w + (size_t)l * MLPD * DIM, wfc1 + (size_t)l * MLPD * DIM, DIM,
        fc1_b + l * MLPD, MTOK, MLPD, DIM, h1, nullptr, nullptr, nullptr);
    launch_gemm<EPI_RESID, 64>(stream, usebf, h1, MLPD,
        fc2_w + (size_t)l * DIM * MLPD, wfc2 + (size_t)l * DIM * MLPD, MLPD,
        fc2_b + l * DIM, MTOK, DIM, MLPD, x, nullptr, nullptr, nullptr, nullptr, nullptr, nullptr);
  }

  // prune: top-98 by norm (+cls), compact to 100 slots/image
  norms_kernel<<<(MTOK + 3) / 4, 256, 0, stream>>>(x, norms);
  topk_select<<<BATCH, 256, 0, stream>>>(norms, sidx, cnt);
  gather_kernel<<<MCTOK, 192, 0, stream>>>(x, sidx, xc);

  // layers 4..11: compact tokens; 128-tile GEMMs (grids 900/1200, 6 blk/CU)
  for (int l = 4; l < 12; ++l) {
    ln_kernel<<<MCTOK, 192, 0, stream>>>(xc, DIM, ln1_w + l * DIM, ln1_b + l * DIM, xn);
    launch_gemm<EPI_QKVC, 128>(stream, usebf, xn, DIM,
        qkv_w + (size_t)l * 2304 * DIM, wqkv + (size_t)l * 2304 * DIM, DIM,
        qkv_b + l * 2304, MCTOK, 2304, DIM, nullptr, nullptr, nullptr, qb, kb, vb, nullptr);
    attn_kernel<7, CSLOT, VLDC, 136, true><<<BATCH * NH, 256, 0, stream>>>(qb, kb, vb, cnt, xn);
    launch_gemm<EPI_RESID, 64>(stream, usebf, xn, DIM,
        proj_w + (size_t)l * DIM * DIM, wproj + (size_t)l * DIM * DIM, DIM,
        proj_b + l * DIM, MCTOK, DIM, DIM, xc, nullptr, nullptr, nullptr, nullptr, nullptr, nullptr);
    ln_kernel<<<MCTOK, 192, 0, stream>>>(xc, DIM, ln2_w + l * DIM, ln2_b + l * DIM, xn);
    launch_gemm<EPI_GELU, 128>(stream, usebf, xn, DIM,
        fc1_w + (size_t)l * MLPD * DIM, wfc1 + (size_t)l * MLPD * DIM, DIM,
        fc1_b + l * MLPD, MCTOK, MLPD, DIM, nullptr, nullptr, h1, nullptr, nullptr, nullptr, nullptr);
    launch_gemm<EPI_RESID, 64>(stream, usebf, h1, MLPD,
        fc2_w + (size_t)l * DIM * MLPD, wfc2 + (size_t)l * DIM * MLPD, MLPD,
        fc2_b + l * DIM, MCTOK, DIM, MLPD, xc, nullptr, nullptr, nullptr, nullptr, nullptr, nullptr);
  }

  ln_kernel<<<64, 192, 0, stream>>>(xc, (long long)CSLOT * DIM, norm_w, norm_b, lncls);
  launch_gemm<EPI_HEAD, 64>(stream, usebf, lncls, DIM, head_w, whead, DIM,
      head_b, 64, 1000, DIM, nullptr, nullptr, nullptr, nullptr, nullptr, nullptr, (float*)d_out);
  (void)in_sizes; (void)n_in; (void)out_size;
}